// Round 2
// baseline (121.220 us; speedup 1.0000x reference)
//
#include <hip/hip_runtime.h>
#include <math.h>

#define NB 2
#define NTOK 16384
#define CDIM 64
#define WIMG 128
#define NKV 256
#define NHEAD 8
#define HDIM 8
#define KTOT 4096
#define KSPLIT 16
#define RTOKS 512  // NB*NKV reduced tokens

// softmax scale folded with log2(e) so we can use native exp2
constexpr float KSCALE = 0.35355339059327373f * 1.4426950408889634f;

__device__ __forceinline__ float wave_reduce_sum64(float v) {
  #pragma unroll
  for (int off = 32; off > 0; off >>= 1) v += __shfl_xor(v, off, 64);
  return v;
}

// ---------------- K0: transpose conv weight [O][I][8][8] -> W2T[kk][o], kk = pos*64+i
__global__ __launch_bounds__(256) void k0_transpose_w(const float* __restrict__ srw,
                                                      float* __restrict__ w2t) {
  int idx = blockIdx.x * 256 + threadIdx.x;   // 262144 total
  int kk = idx >> 6;
  int o  = idx & 63;
  int pos = kk >> 6;
  int i   = kk & 63;
  w2t[idx] = srw[(o << 12) + (i << 6) + pos];
}

// ---------------- K1: conv as K-split GEMM. grid (16 token tiles, 16 k-chunks)
__global__ __launch_bounds__(256) void k1_conv_partial(const float* __restrict__ x,
                                                       const float* __restrict__ w2t,
                                                       float* __restrict__ pbuf) {
  __shared__ float xs[32][68];
  __shared__ float ws[64][68];
  const int t = threadIdx.x;
  const int tile = blockIdx.x;   // 0..15
  const int kch  = blockIdx.y;   // 0..15
  // loading indices
  const int lr = t >> 3, li0 = (t & 7) << 3;     // x: 32 rows x 64
  const int tgL = tile * 32 + lr;
  const int bL  = tgL >> 8;
  const int pL  = tgL & 255;
  const int phL = pL >> 4, pwL = pL & 15;
  const int wr = t >> 2, wo0 = (t & 3) << 4;     // w: 64 rows x 64
  // compute indices
  const int tokl = t >> 3;
  const int ob   = (t & 7) << 3;
  float acc[8];
  #pragma unroll
  for (int j = 0; j < 8; ++j) acc[j] = 0.f;

  for (int sc = 0; sc < 4; ++sc) {
    const int k0  = kch * 256 + sc * 64;   // 64-aligned chunk == one conv tap position
    const int pos = k0 >> 6;
    const int kh = pos >> 3, kw = pos & 7;
    const int nrow = (phL * 8 + kh) * WIMG + (pwL * 8 + kw);
    const float* xsrc = x + ((size_t)bL * NTOK + nrow) * CDIM + li0;
    float4 a0 = *(const float4*)(xsrc);
    float4 a1 = *(const float4*)(xsrc + 4);
    const float* wsrc = w2t + (size_t)(k0 + wr) * 64 + wo0;
    float4 b0 = *(const float4*)(wsrc);
    float4 b1 = *(const float4*)(wsrc + 4);
    float4 b2 = *(const float4*)(wsrc + 8);
    float4 b3 = *(const float4*)(wsrc + 12);
    __syncthreads();   // previous compute done before overwriting LDS
    *(float4*)&xs[lr][li0]     = a0;
    *(float4*)&xs[lr][li0 + 4] = a1;
    *(float4*)&ws[wr][wo0]      = b0;
    *(float4*)&ws[wr][wo0 + 4]  = b1;
    *(float4*)&ws[wr][wo0 + 8]  = b2;
    *(float4*)&ws[wr][wo0 + 12] = b3;
    __syncthreads();
    #pragma unroll 16
    for (int kk2 = 0; kk2 < 64; ++kk2) {
      const float xv = xs[tokl][kk2];
      #pragma unroll
      for (int j = 0; j < 8; ++j) acc[j] += xv * ws[kk2][ob + j];
    }
  }
  const int tg = tile * 32 + tokl;
  float* dst = pbuf + ((size_t)kch * RTOKS + tg) * 64 + ob;
  #pragma unroll
  for (int j = 0; j < 8; ++j) dst[j] = acc[j];
}

// ---------------- K2: reduce partials + bias + layernorm + KV projection
__global__ __launch_bounds__(64) void k2_ln_kv(const float* __restrict__ pbuf,
                                               const float* __restrict__ srb,
                                               const float* __restrict__ lng,
                                               const float* __restrict__ lnb,
                                               const float* __restrict__ kvw,
                                               float* __restrict__ kbuf,
                                               float* __restrict__ vbuf) {
  __shared__ float ylds[64];
  const int tg = blockIdx.x;    // 0..511 reduced token
  const int o  = threadIdx.x;   // 0..63 channel
  float y = srb[o];
  #pragma unroll
  for (int s = 0; s < KSPLIT; ++s) y += pbuf[((size_t)s * RTOKS + tg) * 64 + o];
  const float sum   = wave_reduce_sum64(y);
  const float sumsq = wave_reduce_sum64(y * y);
  const float mu  = sum * (1.f / 64.f);
  const float var = sumsq * (1.f / 64.f) - mu * mu;
  const float rstd = rsqrtf(var + 1e-5f);
  const float yn = (y - mu) * rstd * lng[o] + lnb[o];
  ylds[o] = yn;
  __syncthreads();
  float ka = 0.f, va = 0.f;
  #pragma unroll 16
  for (int i = 0; i < 64; ++i) {
    const float yv = ylds[i];
    ka += yv * kvw[i * 128 + o];
    va += yv * kvw[i * 128 + 64 + o];
  }
  const int b = tg >> 8, p = tg & 255;
  const int h = o >> 3, d = o & 7;
  const size_t idx = (((size_t)b * NHEAD + h) * NKV + p) * HDIM + d;
  kbuf[idx] = ka * KSCALE;   // fold softmax scale * log2e into K
  vbuf[idx] = va;
}

// ---------------- K3: q = x @ q_w, stored head-major [B][H][N][8]
__global__ __launch_bounds__(256) void k3_qproj(const float* __restrict__ x,
                                                const float* __restrict__ qw,
                                                float* __restrict__ qbuf) {
  __shared__ float xs[64][68];
  __shared__ float wsq[64][68];
  const int t = threadIdx.x;
  const int blk = blockIdx.x;          // 0..511
  const int b = blk >> 8;
  const int tok0 = (blk & 255) * 64;
  const int lr = t >> 2, lc0 = (t & 3) << 4;
  {
    const float* src = x + ((size_t)b * NTOK + tok0 + lr) * CDIM + lc0;
    float4 v0 = *(const float4*)(src);
    float4 v1 = *(const float4*)(src + 4);
    float4 v2 = *(const float4*)(src + 8);
    float4 v3 = *(const float4*)(src + 12);
    *(float4*)&xs[lr][lc0]      = v0;
    *(float4*)&xs[lr][lc0 + 4]  = v1;
    *(float4*)&xs[lr][lc0 + 8]  = v2;
    *(float4*)&xs[lr][lc0 + 12] = v3;
    const float* wsrc = qw + lr * 64 + lc0;
    float4 w0 = *(const float4*)(wsrc);
    float4 w1 = *(const float4*)(wsrc + 4);
    float4 w2 = *(const float4*)(wsrc + 8);
    float4 w3 = *(const float4*)(wsrc + 12);
    *(float4*)&wsq[lr][lc0]      = w0;
    *(float4*)&wsq[lr][lc0 + 4]  = w1;
    *(float4*)&wsq[lr][lc0 + 8]  = w2;
    *(float4*)&wsq[lr][lc0 + 12] = w3;
  }
  __syncthreads();
  const int tok = t >> 2, cb = (t & 3) << 4;
  float acc[16];
  #pragma unroll
  for (int j = 0; j < 16; ++j) acc[j] = 0.f;
  #pragma unroll 16
  for (int c = 0; c < 64; ++c) {
    const float xv = xs[tok][c];
    #pragma unroll
    for (int j = 0; j < 16; ++j) acc[j] += xv * wsq[c][cb + j];
  }
  const int tokg = tok0 + tok;
  #pragma unroll
  for (int g = 0; g < 2; ++g) {
    const int h = (cb >> 3) + g;
    float* dst = qbuf + (((size_t)b * NHEAD + h) * NTOK + tokg) * HDIM;
    float4 w0 = make_float4(acc[g*8+0], acc[g*8+1], acc[g*8+2], acc[g*8+3]);
    float4 w1 = make_float4(acc[g*8+4], acc[g*8+5], acc[g*8+6], acc[g*8+7]);
    *(float4*)(dst)     = w0;
    *(float4*)(dst + 4) = w1;
  }
}

// ---------------- K4 v2: attention, 1 token/thread, K/V via wave-uniform scalar loads
// K/V addresses depend only on blockIdx + loop counter -> compiler emits s_load,
// values live in SGPRs, consumed directly by v_fma (1 SGPR operand allowed).
// No LDS at all; K/V (16 KB per bh) is L2-resident.
__global__ __launch_bounds__(256) void k4_attn(const float* __restrict__ qbuf,
                                               const float* __restrict__ kbuf,
                                               const float* __restrict__ vbuf,
                                               float* __restrict__ abuf) {
  const int t = threadIdx.x;
  const int tile = blockIdx.x;   // 64 tiles of 256 tokens
  const int h = blockIdx.y;
  const int b = blockIdx.z;
  const size_t bh = (size_t)b * NHEAD + h;
  const int tok = tile * 256 + t;
  const float* qp = qbuf + (bh * NTOK + tok) * HDIM;
  const float4 q0 = *(const float4*)qp;
  const float4 q1 = *(const float4*)(qp + 4);
  const float* kp = kbuf + bh * NKV * HDIM;   // wave-uniform
  const float* vp = vbuf + bh * NKV * HDIM;   // wave-uniform

  float4 a0 = make_float4(0.f, 0.f, 0.f, 0.f);
  float4 a1 = make_float4(0.f, 0.f, 0.f, 0.f);
  float l = 0.f;
  #pragma unroll 8
  for (int j = 0; j < NKV; ++j) {
    const float* kj = kp + j * HDIM;
    const float* vj = vp + j * HDIM;
    const float s = ((q0.x * kj[0] + q0.y * kj[1]) + (q0.z * kj[2] + q0.w * kj[3]))
                  + ((q1.x * kj[4] + q1.y * kj[5]) + (q1.z * kj[6] + q1.w * kj[7]));
    const float e = exp2f(s);
    l += e;
    a0.x += e * vj[0]; a0.y += e * vj[1]; a0.z += e * vj[2]; a0.w += e * vj[3];
    a1.x += e * vj[4]; a1.y += e * vj[5]; a1.z += e * vj[6]; a1.w += e * vj[7];
  }
  const float r = 1.0f / l;
  float* da = abuf + (bh * NTOK + tok) * HDIM;
  *(float4*)(da)     = make_float4(a0.x * r, a0.y * r, a0.z * r, a0.w * r);
  *(float4*)(da + 4) = make_float4(a1.x * r, a1.y * r, a1.z * r, a1.w * r);
}

// ---------------- K5: output projection + bias
__global__ __launch_bounds__(256) void k5_proj(const float* __restrict__ abuf,
                                               const float* __restrict__ pw,
                                               const float* __restrict__ pb,
                                               float* __restrict__ out) {
  __shared__ float as_[64][68];
  __shared__ float wsp[64][68];
  const int t = threadIdx.x;
  const int blk = blockIdx.x;  // 0..511
  const int b = blk >> 8;
  const int tok0 = (blk & 255) * 64;
  {
    // gather head-major attn-out into token-major LDS tile
    const int h = t >> 5;                    // t/32: head slice (512 floats each)
    const int rem = (t & 31) << 4;           // 0..496 within slice, 16 floats per thread
    const int tokL = rem >> 3;               // even token index, covers tokL, tokL+1
    const float* src = abuf + (((size_t)b * NHEAD + h) * NTOK + tok0 + tokL) * HDIM;
    float4 v0 = *(const float4*)(src);
    float4 v1 = *(const float4*)(src + 4);
    float4 v2 = *(const float4*)(src + 8);
    float4 v3 = *(const float4*)(src + 12);
    *(float4*)&as_[tokL][h * 8]         = v0;
    *(float4*)&as_[tokL][h * 8 + 4]     = v1;
    *(float4*)&as_[tokL + 1][h * 8]     = v2;
    *(float4*)&as_[tokL + 1][h * 8 + 4] = v3;
    const int wr = t >> 2, wc0 = (t & 3) << 4;
    const float* wsrc = pw + wr * 64 + wc0;
    float4 w0 = *(const float4*)(wsrc);
    float4 w1 = *(const float4*)(wsrc + 4);
    float4 w2 = *(const float4*)(wsrc + 8);
    float4 w3 = *(const float4*)(wsrc + 12);
    *(float4*)&wsp[wr][wc0]      = w0;
    *(float4*)&wsp[wr][wc0 + 4]  = w1;
    *(float4*)&wsp[wr][wc0 + 8]  = w2;
    *(float4*)&wsp[wr][wc0 + 12] = w3;
  }
  __syncthreads();
  const int tok = t >> 2, cb = (t & 3) << 4;
  float acc[16];
  #pragma unroll
  for (int j = 0; j < 16; ++j) acc[j] = 0.f;
  #pragma unroll 16
  for (int c = 0; c < 64; ++c) {
    const float xv = as_[tok][c];
    #pragma unroll
    for (int j = 0; j < 16; ++j) acc[j] += xv * wsp[c][cb + j];
  }
  float* dst = out + ((size_t)b * NTOK + tok0 + tok) * CDIM + cb;
  #pragma unroll
  for (int j = 0; j < 16; ++j) acc[j] += pb[cb + j];
  *(float4*)(dst)      = make_float4(acc[0], acc[1], acc[2], acc[3]);
  *(float4*)(dst + 4)  = make_float4(acc[4], acc[5], acc[6], acc[7]);
  *(float4*)(dst + 8)  = make_float4(acc[8], acc[9], acc[10], acc[11]);
  *(float4*)(dst + 12) = make_float4(acc[12], acc[13], acc[14], acc[15]);
}

extern "C" void kernel_launch(void* const* d_in, const int* in_sizes, int n_in,
                              void* d_out, int out_size, void* d_ws, size_t ws_size,
                              hipStream_t stream) {
  const float* x    = (const float*)d_in[0];
  // d_in[1], d_in[2] are H, W scalars (128, 128) — fixed by the problem
  const float* qw   = (const float*)d_in[3];
  const float* kvw  = (const float*)d_in[4];
  const float* srw  = (const float*)d_in[5];
  const float* srb  = (const float*)d_in[6];
  const float* lng  = (const float*)d_in[7];
  const float* lnb  = (const float*)d_in[8];
  const float* pw   = (const float*)d_in[9];
  const float* pb   = (const float*)d_in[10];
  float* out = (float*)d_out;
  float* ws  = (float*)d_ws;

  float* w2t  = ws;                 // 262144 floats (transposed conv weight)
  float* pbuf = ws + 262144;        // 524288 floats (conv K-split partials)
  float* kbuf = ws + 786432;        // 32768 floats
  float* vbuf = ws + 819200;        // 32768 floats
  float* qbuf = ws + 851968;        // 2097152 floats
  float* abuf = ws + 2949120;       // 2097152 floats

  k0_transpose_w<<<1024, 256, 0, stream>>>(srw, w2t);
  k1_conv_partial<<<dim3(16, 16), 256, 0, stream>>>(x, w2t, pbuf);
  k2_ln_kv<<<512, 64, 0, stream>>>(pbuf, srb, lng, lnb, kvw, kbuf, vbuf);
  k3_qproj<<<512, 256, 0, stream>>>(x, qw, qbuf);
  k4_attn<<<dim3(64, NHEAD, NB), 256, 0, stream>>>(qbuf, kbuf, vbuf, abuf);
  k5_proj<<<512, 256, 0, stream>>>(abuf, pw, pb, out);
}

// Round 4
// 59.550 us; speedup vs baseline: 2.0356x; 2.0356x over previous
//
#include <hip/hip_runtime.h>
#include <math.h>

#define NB 2
#define NTOK 16384
#define CDIM 64
#define WIMG 128
#define NKV 256
#define NHEAD 8
#define HDIM 8
#define KTOT 4096
#define KSPLIT 16
#define RTOKS 512  // NB*NKV reduced tokens

typedef unsigned short u16;
typedef __attribute__((ext_vector_type(8))) short bf16x8;   // 8 bf16 = 4 VGPRs
typedef __attribute__((ext_vector_type(4))) unsigned int u32x4;
typedef __attribute__((ext_vector_type(2))) unsigned int u32x2;
typedef __attribute__((ext_vector_type(16))) float f32x16;

// softmax scale folded with log2(e), applied to K before bf16 quantization
constexpr float KSCALE = 0.35355339059327373f * 1.4426950408889634f;

__device__ __forceinline__ u16 f2bf(float f) {   // RNE f32->bf16
  unsigned u = __builtin_bit_cast(unsigned, f);
  return (u16)((u + 0x7FFFu + ((u >> 16) & 1u)) >> 16);
}

__device__ __forceinline__ f32x16 mfma32x16(bf16x8 a, bf16x8 b, f32x16 c) {
#if __has_builtin(__builtin_amdgcn_mfma_f32_32x32x16_bf16)
  return __builtin_amdgcn_mfma_f32_32x32x16_bf16(a, b, c, 0, 0, 0);
#else
  asm volatile("v_mfma_f32_32x32x16_bf16 %0, %1, %2, %0\n\t"
               "s_nop 7\n\ts_nop 7\n\ts_nop 3"
               : "+v"(c) : "v"(a), "v"(b));
  return c;
#endif
}

__device__ __forceinline__ void pl32swap(unsigned &a, unsigned &b) {
#if __has_builtin(__builtin_amdgcn_permlane32_swap)
  u32x2 r = __builtin_amdgcn_permlane32_swap(a, b, false, false);
  a = r[0]; b = r[1];
#else
  asm volatile("v_permlane32_swap_b32 %0, %1" : "+v"(a), "+v"(b));
#endif
}

__device__ __forceinline__ float fexp2(float x) {
#if __has_builtin(__builtin_amdgcn_exp2f)
  return __builtin_amdgcn_exp2f(x);
#else
  float r;
  asm("v_exp_f32 %0, %1" : "=v"(r) : "v"(x));
  return r;
#endif
}

__device__ __forceinline__ float wave_reduce_sum64(float v) {
  #pragma unroll
  for (int off = 32; off > 0; off >>= 1) v += __shfl_xor(v, off, 64);
  return v;
}

// ---------------- K0: transpose conv weight [O][I][8][8] -> W2T[kk][o], kk = pos*64+i
__global__ __launch_bounds__(256) void k0_transpose_w(const float* __restrict__ srw,
                                                      float* __restrict__ w2t) {
  int idx = blockIdx.x * 256 + threadIdx.x;   // 262144 total
  int kk = idx >> 6;
  int o  = idx & 63;
  int pos = kk >> 6;
  int i   = kk & 63;
  w2t[idx] = srw[(o << 12) + (i << 6) + pos];
}

// ---------------- K1: conv as K-split GEMM. grid (16 token tiles, 16 k-chunks)
__global__ __launch_bounds__(256) void k1_conv_partial(const float* __restrict__ x,
                                                       const float* __restrict__ w2t,
                                                       float* __restrict__ pbuf) {
  __shared__ float xs[32][68];
  __shared__ float ws[64][68];
  const int t = threadIdx.x;
  const int tile = blockIdx.x;   // 0..15
  const int kch  = blockIdx.y;   // 0..15
  const int lr = t >> 3, li0 = (t & 7) << 3;     // x: 32 rows x 64
  const int tgL = tile * 32 + lr;
  const int bL  = tgL >> 8;
  const int pL  = tgL & 255;
  const int phL = pL >> 4, pwL = pL & 15;
  const int wr = t >> 2, wo0 = (t & 3) << 4;     // w: 64 rows x 64
  const int tokl = t >> 3;
  const int ob   = (t & 7) << 3;
  float acc[8];
  #pragma unroll
  for (int j = 0; j < 8; ++j) acc[j] = 0.f;

  for (int sc = 0; sc < 4; ++sc) {
    const int k0  = kch * 256 + sc * 64;   // 64-aligned chunk == one conv tap position
    const int pos = k0 >> 6;
    const int kh = pos >> 3, kw = pos & 7;
    const int nrow = (phL * 8 + kh) * WIMG + (pwL * 8 + kw);
    const float* xsrc = x + ((size_t)bL * NTOK + nrow) * CDIM + li0;
    float4 a0 = *(const float4*)(xsrc);
    float4 a1 = *(const float4*)(xsrc + 4);
    const float* wsrc = w2t + (size_t)(k0 + wr) * 64 + wo0;
    float4 b0 = *(const float4*)(wsrc);
    float4 b1 = *(const float4*)(wsrc + 4);
    float4 b2 = *(const float4*)(wsrc + 8);
    float4 b3 = *(const float4*)(wsrc + 12);
    __syncthreads();
    *(float4*)&xs[lr][li0]     = a0;
    *(float4*)&xs[lr][li0 + 4] = a1;
    *(float4*)&ws[wr][wo0]      = b0;
    *(float4*)&ws[wr][wo0 + 4]  = b1;
    *(float4*)&ws[wr][wo0 + 8]  = b2;
    *(float4*)&ws[wr][wo0 + 12] = b3;
    __syncthreads();
    #pragma unroll 16
    for (int kk2 = 0; kk2 < 64; ++kk2) {
      const float xv = xs[tokl][kk2];
      #pragma unroll
      for (int j = 0; j < 8; ++j) acc[j] += xv * ws[kk2][ob + j];
    }
  }
  const int tg = tile * 32 + tokl;
  float* dst = pbuf + ((size_t)kch * RTOKS + tg) * 64 + ob;
  #pragma unroll
  for (int j = 0; j < 8; ++j) dst[j] = acc[j];
}

// ---------------- K2: reduce partials + bias + LN + KV proj -> bf16 K (scaled), bf16 V^T
__global__ __launch_bounds__(64) void k2_ln_kv(const float* __restrict__ pbuf,
                                               const float* __restrict__ srb,
                                               const float* __restrict__ lng,
                                               const float* __restrict__ lnb,
                                               const float* __restrict__ kvw,
                                               u16* __restrict__ kbuf,
                                               u16* __restrict__ vbufT) {
  __shared__ float ylds[64];
  const int tg = blockIdx.x;    // 0..511 reduced token
  const int o  = threadIdx.x;   // 0..63 channel
  float y = srb[o];
  #pragma unroll
  for (int s = 0; s < KSPLIT; ++s) y += pbuf[((size_t)s * RTOKS + tg) * 64 + o];
  const float sum   = wave_reduce_sum64(y);
  const float sumsq = wave_reduce_sum64(y * y);
  const float mu  = sum * (1.f / 64.f);
  const float var = sumsq * (1.f / 64.f) - mu * mu;
  const float rstd = rsqrtf(var + 1e-5f);
  const float yn = (y - mu) * rstd * lng[o] + lnb[o];
  ylds[o] = yn;
  __syncthreads();
  float ka = 0.f, va = 0.f;
  #pragma unroll 16
  for (int i = 0; i < 64; ++i) {
    const float yv = ylds[i];
    ka += yv * kvw[i * 128 + o];
    va += yv * kvw[i * 128 + 64 + o];
  }
  const int b = tg >> 8, p = tg & 255;
  const int h = o >> 3, d = o & 7;
  const int bh = b * NHEAD + h;
  kbuf[((size_t)bh * NKV + p) * HDIM + d] = f2bf(ka * KSCALE);
  vbufT[((size_t)bh * HDIM + d) * NKV + p] = f2bf(va);
}

// ---------------- K3: q = x @ q_w, stored head-major bf16 [B][H][N][8]
__global__ __launch_bounds__(256) void k3_qproj(const float* __restrict__ x,
                                                const float* __restrict__ qw,
                                                u16* __restrict__ qbuf) {
  __shared__ float xs[64][68];
  __shared__ float wsq[64][68];
  const int t = threadIdx.x;
  const int blk = blockIdx.x;          // 0..511
  const int b = blk >> 8;
  const int tok0 = (blk & 255) * 64;
  const int lr = t >> 2, lc0 = (t & 3) << 4;
  {
    const float* src = x + ((size_t)b * NTOK + tok0 + lr) * CDIM + lc0;
    float4 v0 = *(const float4*)(src);
    float4 v1 = *(const float4*)(src + 4);
    float4 v2 = *(const float4*)(src + 8);
    float4 v3 = *(const float4*)(src + 12);
    *(float4*)&xs[lr][lc0]      = v0;
    *(float4*)&xs[lr][lc0 + 4]  = v1;
    *(float4*)&xs[lr][lc0 + 8]  = v2;
    *(float4*)&xs[lr][lc0 + 12] = v3;
    const float* wsrc = qw + lr * 64 + lc0;
    float4 w0 = *(const float4*)(wsrc);
    float4 w1 = *(const float4*)(wsrc + 4);
    float4 w2 = *(const float4*)(wsrc + 8);
    float4 w3 = *(const float4*)(wsrc + 12);
    *(float4*)&wsq[lr][lc0]      = w0;
    *(float4*)&wsq[lr][lc0 + 4]  = w1;
    *(float4*)&wsq[lr][lc0 + 8]  = w2;
    *(float4*)&wsq[lr][lc0 + 12] = w3;
  }
  __syncthreads();
  const int tok = t >> 2, cb = (t & 3) << 4;
  float acc[16];
  #pragma unroll
  for (int j = 0; j < 16; ++j) acc[j] = 0.f;
  #pragma unroll 16
  for (int c = 0; c < 64; ++c) {
    const float xv = xs[tok][c];
    #pragma unroll
    for (int j = 0; j < 16; ++j) acc[j] += xv * wsq[c][cb + j];
  }
  const int tokg = tok0 + tok;
  #pragma unroll
  for (int g = 0; g < 2; ++g) {
    const int h = (cb >> 3) + g;
    const int bh = b * NHEAD + h;
    u16* dst = qbuf + ((size_t)bh * NTOK + tokg) * HDIM;
    uint4 w;
    w.x = (unsigned)f2bf(acc[g*8+0]) | ((unsigned)f2bf(acc[g*8+1]) << 16);
    w.y = (unsigned)f2bf(acc[g*8+2]) | ((unsigned)f2bf(acc[g*8+3]) << 16);
    w.z = (unsigned)f2bf(acc[g*8+4]) | ((unsigned)f2bf(acc[g*8+5]) << 16);
    w.w = (unsigned)f2bf(acc[g*8+6]) | ((unsigned)f2bf(acc[g*8+7]) << 16);
    *(uint4*)dst = w;
  }
}

// ---------------- K4 v4: MFMA attention via verified mfma_f32_32x32x16_bf16.
// S^T = K·Q^T (A=K rows zero-padded to k=16, B=Q^T). C layout (m74/m101):
// col=lane&31, row=(reg&3)+8*(reg>>2)+4*(lane>>5). PV B-frags (k=8*hi+i) are
// built from C reg-quads with 8 cvt_pk + 4 permlane32_swap per 32-key block
// (T12). Denominator accumulated in VALU + one shfl_xor(32).
__global__ __launch_bounds__(256) void k4_attn_mfma(const u16* __restrict__ qbuf,
                                                    const u16* __restrict__ kbuf,
                                                    const u16* __restrict__ vbufT,
                                                    float* __restrict__ abuf) {
  const int t = threadIdx.x;
  const int lane = t & 63;
  const int w = blockIdx.x * 4 + (t >> 6);   // global wave id, 0..2047
  const int bh = w >> 7;                     // 16 (b,h) pairs, 128 waves each
  const int wi = w & 127;
  const int lo = lane & 31;
  const int hi = lane >> 5;

  // K fragments: A[m=key][k]; hi=0 lanes hold k=0..7 = K row (16B load); hi=1 -> zero pad
  bf16x8 kf[8];
  const u16* kb = kbuf + (size_t)bh * NKV * HDIM;
  #pragma unroll
  for (int c = 0; c < 8; ++c) {
    bf16x8 z = {0, 0, 0, 0, 0, 0, 0, 0};
    if (hi == 0) z = *(const bf16x8*)(kb + (c * 32 + lo) * HDIM);
    kf[c] = z;
  }

  // V^T fragments: A[m=d][k=key]; frag f covers keys f*16..f*16+15; lane supplies
  // k = 8*hi + i -> V^T[lo][f*16 + hi*8 + i] (16B load); rows d>=8 are zero.
  bf16x8 vf[16];
  const u16* vb = vbufT + (size_t)bh * HDIM * NKV;
  #pragma unroll
  for (int f = 0; f < 16; ++f) {
    bf16x8 z = {0, 0, 0, 0, 0, 0, 0, 0};
    if (lo < 8) z = *(const bf16x8*)(vb + lo * NKV + f * 16 + hi * 8);
    vf[f] = z;
  }

  #pragma unroll
  for (int c = 0; c < 4; ++c) {
    const int qt = (wi * 4 + c) * 32;
    // Q^T fragment: B[k][n=query]; hi=0 lanes hold k=0..7 = Q row; hi=1 zero pad
    bf16x8 qf = {0, 0, 0, 0, 0, 0, 0, 0};
    if (hi == 0) qf = *(const bf16x8*)(qbuf + ((size_t)bh * NTOK + qt + lo) * HDIM);

    f32x16 oacc;
    #pragma unroll
    for (int i = 0; i < 16; ++i) oacc[i] = 0.f;
    float den = 0.f;

    #pragma unroll
    for (int kblk = 0; kblk < 8; ++kblk) {
      f32x16 s;
      #pragma unroll
      for (int i = 0; i < 16; ++i) s[i] = 0.f;
      s = mfma32x16(kf[kblk], qf, s);   // S^T tile: rows=keys kblk*32+.., cols=queries

      float p[16];
      #pragma unroll
      for (int r = 0; r < 16; ++r) p[r] = fexp2(s[r]);
      #pragma unroll
      for (int r = 0; r < 16; ++r) den += p[r];

      // pack reg-quads to bf16 pairs: quad q holds S^T rows {q*8/..}: pk01/pk23
      unsigned pk01[4], pk23[4];
      #pragma unroll
      for (int q = 0; q < 4; ++q) {
        asm("v_cvt_pk_bf16_f32 %0, %1, %2" : "=v"(pk01[q]) : "v"(p[4*q+0]), "v"(p[4*q+1]));
        asm("v_cvt_pk_bf16_f32 %0, %1, %2" : "=v"(pk23[q]) : "v"(p[4*q+2]), "v"(p[4*q+3]));
      }

      // mfma jj consumes keys kblk*32 + jj*16 + (8*hi + i).
      // swap(quads 2jj, 2jj+1): result0 = words k=8hi+{0,1}/{2,3}, result1 = k=8hi+{4,5}/{6,7}
      #pragma unroll
      for (int jj = 0; jj < 2; ++jj) {
        unsigned a0 = pk01[2*jj], b0 = pk01[2*jj+1];
        unsigned a1 = pk23[2*jj], b1 = pk23[2*jj+1];
        pl32swap(a0, b0);   // a0 -> word0 (k 0,1), b0 -> word2 (k 4,5)
        pl32swap(a1, b1);   // a1 -> word1 (k 2,3), b1 -> word3 (k 6,7)
        u32x4 wv; wv[0] = a0; wv[1] = a1; wv[2] = b0; wv[3] = b1;
        bf16x8 pfrag = __builtin_bit_cast(bf16x8, wv);
        oacc = mfma32x16(vf[kblk * 2 + jj], pfrag, oacc);
      }
    }

    // Epilogue: O^T col=query=lo; hi=0 lane regs0-3 = d0..3, hi=1 lane regs0-3 = d4..7.
    // den so far covers this lane's 16 S^T rows; partner holds the other 16.
    den += __shfl_xor(den, 32, 64);
    const float r = 1.0f / den;
    float4 o;
    o.x = oacc[0] * r; o.y = oacc[1] * r; o.z = oacc[2] * r; o.w = oacc[3] * r;
    *(float4*)(abuf + ((size_t)bh * NTOK + qt + lo) * HDIM + hi * 4) = o;
  }
}

// ---------------- K5: output projection + bias
__global__ __launch_bounds__(256) void k5_proj(const float* __restrict__ abuf,
                                               const float* __restrict__ pw,
                                               const float* __restrict__ pb,
                                               float* __restrict__ out) {
  __shared__ float as_[64][68];
  __shared__ float wsp[64][68];
  const int t = threadIdx.x;
  const int blk = blockIdx.x;  // 0..511
  const int b = blk >> 8;
  const int tok0 = (blk & 255) * 64;
  {
    const int h = t >> 5;
    const int rem = (t & 31) << 4;
    const int tokL = rem >> 3;
    const float* src = abuf + (((size_t)b * NHEAD + h) * NTOK + tok0 + tokL) * HDIM;
    float4 v0 = *(const float4*)(src);
    float4 v1 = *(const float4*)(src + 4);
    float4 v2 = *(const float4*)(src + 8);
    float4 v3 = *(const float4*)(src + 12);
    *(float4*)&as_[tokL][h * 8]         = v0;
    *(float4*)&as_[tokL][h * 8 + 4]     = v1;
    *(float4*)&as_[tokL + 1][h * 8]     = v2;
    *(float4*)&as_[tokL + 1][h * 8 + 4] = v3;
    const int wr = t >> 2, wc0 = (t & 3) << 4;
    const float* wsrc = pw + wr * 64 + wc0;
    float4 w0 = *(const float4*)(wsrc);
    float4 w1 = *(const float4*)(wsrc + 4);
    float4 w2 = *(const float4*)(wsrc + 8);
    float4 w3 = *(const float4*)(wsrc + 12);
    *(float4*)&wsp[wr][wc0]      = w0;
    *(float4*)&wsp[wr][wc0 + 4]  = w1;
    *(float4*)&wsp[wr][wc0 + 8]  = w2;
    *(float4*)&wsp[wr][wc0 + 12] = w3;
  }
  __syncthreads();
  const int tok = t >> 2, cb = (t & 3) << 4;
  float acc[16];
  #pragma unroll
  for (int j = 0; j < 16; ++j) acc[j] = 0.f;
  #pragma unroll 16
  for (int c = 0; c < 64; ++c) {
    const float xv = as_[tok][c];
    #pragma unroll
    for (int j = 0; j < 16; ++j) acc[j] += xv * wsp[c][cb + j];
  }
  float* dst = out + ((size_t)b * NTOK + tok0 + tok) * CDIM + cb;
  #pragma unroll
  for (int j = 0; j < 16; ++j) acc[j] += pb[cb + j];
  *(float4*)(dst)      = make_float4(acc[0], acc[1], acc[2], acc[3]);
  *(float4*)(dst + 4)  = make_float4(acc[4], acc[5], acc[6], acc[7]);
  *(float4*)(dst + 8)  = make_float4(acc[8], acc[9], acc[10], acc[11]);
  *(float4*)(dst + 12) = make_float4(acc[12], acc[13], acc[14], acc[15]);
}

extern "C" void kernel_launch(void* const* d_in, const int* in_sizes, int n_in,
                              void* d_out, int out_size, void* d_ws, size_t ws_size,
                              hipStream_t stream) {
  const float* x    = (const float*)d_in[0];
  // d_in[1], d_in[2] are H, W scalars (128, 128) — fixed by the problem
  const float* qw   = (const float*)d_in[3];
  const float* kvw  = (const float*)d_in[4];
  const float* srw  = (const float*)d_in[5];
  const float* srb  = (const float*)d_in[6];
  const float* lng  = (const float*)d_in[7];
  const float* lnb  = (const float*)d_in[8];
  const float* pw   = (const float*)d_in[9];
  const float* pb   = (const float*)d_in[10];
  float* out = (float*)d_out;
  float* ws  = (float*)d_ws;

  float* w2t   = ws;                        // 262144 floats
  float* pbuf  = ws + 262144;               // 524288 floats
  u16*   kbuf  = (u16*)(ws + 786432);       // 32768 bf16  (16384 floats)
  u16*   vbufT = (u16*)(ws + 802816);       // 32768 bf16  (16384 floats)
  u16*   qbuf  = (u16*)(ws + 819200);       // 2097152 bf16 (1048576 floats)
  float* abuf  = ws + 1867776;              // 2097152 floats

  k0_transpose_w<<<1024, 256, 0, stream>>>(srw, w2t);
  k1_conv_partial<<<dim3(16, 16), 256, 0, stream>>>(x, w2t, pbuf);
  k2_ln_kv<<<512, 64, 0, stream>>>(pbuf, srb, lng, lnb, kvw, kbuf, vbufT);
  k3_qproj<<<512, 256, 0, stream>>>(x, qw, qbuf);
  k4_attn_mfma<<<512, 256, 0, stream>>>(qbuf, kbuf, vbufT, abuf);
  k5_proj<<<512, 256, 0, stream>>>(abuf, pw, pb, out);
}